// Round 1
// 284.870 us; speedup vs baseline: 1.2399x; 1.2399x over previous
//
#include <hip/hip_runtime.h>
#include <cstdint>
#include <cstddef>

#define DIN 1280
#define DOUT 3840
#define NEXP 6
#define RANK 16
#define TOKENS 16384
#define KPAD 1408   // 1280 x + 16 shared + 96 routed + 16 zero pad
#define NLOW 128    // padded low-rank cols (112 valid)

typedef __bf16 bf16x8 __attribute__((ext_vector_type(8)));
typedef float f32x4 __attribute__((ext_vector_type(4)));
typedef unsigned short u16x8 __attribute__((ext_vector_type(8)));

#define SB() __builtin_amdgcn_sched_barrier(0)
#define BAR() __builtin_amdgcn_s_barrier()

__device__ __forceinline__ unsigned short f2bf(float f) {
    unsigned u = __builtin_bit_cast(unsigned, f);
    u += 0x7fff + ((u >> 16) & 1);   // RNE
    return (unsigned short)(u >> 16);
}

__device__ __forceinline__ void async_load16(void* lds, const void* g) {
    __builtin_amdgcn_global_load_lds(
        (const __attribute__((address_space(1))) unsigned int*)g,
        (__attribute__((address_space(3))) unsigned int*)lds, 16, 0, 0);
}

// Build WcatT [DOUT][KPAD] bf16: rows n, cols k. k<1280: base_w[k][n];
// 1280..1295: shared_w2[k-1280][n]; 1296..1391: routed_w2 flat[k-1296][n]; else 0.
__global__ void prep_w2t(const float* __restrict__ base_w,
                         const float* __restrict__ shared_w2,
                         const float* __restrict__ routed_w2,
                         unsigned short* __restrict__ WT) {
    __shared__ unsigned short tile[32][33];
    int k0 = blockIdx.x * 32, n0 = blockIdx.y * 32;
    int tx = threadIdx.x, ty = threadIdx.y;
#pragma unroll
    for (int j = 0; j < 4; j++) {
        int k = k0 + ty + j * 8;
        int n = n0 + tx;
        float v;
        if (k < DIN)            v = base_w[(size_t)k * DOUT + n];
        else if (k < DIN + 16)  v = shared_w2[(size_t)(k - DIN) * DOUT + n];
        else if (k < DIN + 112) v = routed_w2[(size_t)(k - DIN - 16) * DOUT + n];
        else                    v = 0.f;
        tile[ty + j * 8][tx] = f2bf(v);
    }
    __syncthreads();
#pragma unroll
    for (int j = 0; j < 4; j++) {
        int n = n0 + ty + j * 8;
        int k = k0 + tx;
        WT[(size_t)n * KPAD + k] = tile[tx][ty + j * 8];
    }
}

// Build W1catT [NLOW][DIN] bf16: row n<16: shared_w1[:,n]; 16..111: routed_w1[e][:,r]; else 0.
__global__ void prep_w1t(const float* __restrict__ shared_w1,
                         const float* __restrict__ routed_w1,
                         unsigned short* __restrict__ W1T) {
    __shared__ unsigned short tile[32][33];
    int k0 = blockIdx.x * 32, n0 = blockIdx.y * 32;
    int tx = threadIdx.x, ty = threadIdx.y;
#pragma unroll
    for (int j = 0; j < 4; j++) {
        int k = k0 + ty + j * 8;
        int n = n0 + tx;
        float v = 0.f;
        if (n < 16) v = shared_w1[k * RANK + n];
        else if (n < 112) {
            int jj = n - 16, e = jj >> 4, r = jj & 15;
            v = routed_w1[(size_t)e * DIN * RANK + k * RANK + r];
        }
        tile[ty + j * 8][tx] = f2bf(v);
    }
    __syncthreads();
#pragma unroll
    for (int j = 0; j < 4; j++) {
        int n = n0 + ty + j * 8;
        int k = k0 + tx;
        W1T[(size_t)n * DIN + k] = tile[tx][ty + j * 8];
    }
}

// Per 8-token block: convert x -> bf16 into A[:, 0:1280] (vectorized 8-wide),
// zero A[:, 1392:1408], fp32 router logits -> softmax -> top-3 -> cw[T,6].
__global__ __launch_bounds__(256) void router_kernel(
    const float* __restrict__ x,
    const float* __restrict__ router_w,
    const float* __restrict__ router_b,
    unsigned short* __restrict__ A,
    float* __restrict__ cw) {
    int tid = threadIdx.x;
    size_t t0 = (size_t)blockIdx.x * 8;
    const float* xblk = x + t0 * DIN;
    unsigned short* Ablk = A + t0 * KPAD;

    // 8 tokens * 160 8-element chunks; f32x4 x2 load + 16B bf16 store (G13)
    for (int i = tid; i < 8 * (DIN / 8); i += 256) {
        int t = i / (DIN / 8), c = (i - t * (DIN / 8)) * 8;
        const float* xs = xblk + (size_t)t * DIN + c;
        f32x4 v0 = *(const f32x4*)xs;
        f32x4 v1 = *(const f32x4*)(xs + 4);
        u16x8 o;
#pragma unroll
        for (int j = 0; j < 4; j++) { o[j] = f2bf(v0[j]); o[4 + j] = f2bf(v1[j]); }
        *(u16x8*)&Ablk[(size_t)t * KPAD + c] = o;
    }
    if (tid < 128) {
        int t = tid >> 4, c = tid & 15;
        Ablk[t * KPAD + DIN + 112 + c] = 0;
    }

    int tg = tid >> 5, lj = tid & 31;
    const float* xt = xblk + (size_t)tg * DIN;
    float acc[6] = {0.f, 0.f, 0.f, 0.f, 0.f, 0.f};
    for (int k = lj; k < DIN; k += 32) {
        float xv = xt[k];
        const float* wr = router_w + k * NEXP;
#pragma unroll
        for (int e = 0; e < NEXP; e++) acc[e] = fmaf(xv, wr[e], acc[e]);
    }
#pragma unroll
    for (int off = 16; off > 0; off >>= 1)
#pragma unroll
        for (int e = 0; e < NEXP; e++) acc[e] += __shfl_xor(acc[e], off);

    float mx = -1e30f;
#pragma unroll
    for (int e = 0; e < NEXP; e++) { acc[e] += router_b[e]; mx = fmaxf(mx, acc[e]); }
    float g[6]; float s = 0.f;
#pragma unroll
    for (int e = 0; e < NEXP; e++) { g[e] = __expf(acc[e] - mx); s += g[e]; }
    float inv = 1.f / s;
    if (lj < NEXP) {
        float ge = g[lj];
        int cnt = 0;
#pragma unroll
        for (int e = 0; e < NEXP; e++) {
            if (e == lj) continue;
            if (g[e] > ge || (g[e] == ge && e < lj)) cnt++;  // tie -> lowest index wins
        }
        cw[(t0 + tg) * NEXP + lj] = (cnt < 3) ? ge * inv : 0.f;
    }
}

// A[t, 1280+j] = bf16( (j<16 ? 1 : cw[t][(j-16)/16]) * (H0+H1)[t][j] ), j in [0,112)
__global__ __launch_bounds__(256) void combine_kernel(
    const float* __restrict__ H, const float* __restrict__ cw,
    unsigned short* __restrict__ A) {
    int i = blockIdx.x * 256 + threadIdx.x;  // < TOKENS*112
    int t = i / 112, j = i - t * 112;
    float h = H[(size_t)t * NLOW + j] + H[(size_t)TOKENS * NLOW + (size_t)t * NLOW + j];
    float f = (j < 16) ? 1.0f : cw[t * NEXP + ((j - 16) >> 4)];
    A[(size_t)t * KPAD + DIN + j] = f2bf(f * h);
}

// Small GEMM H[z][m,n] = A[m, z*640 : z*640+640] @ W1T[n, z*640 : ...]^T.
// K-split over gridDim.z=2 -> 256 blocks (full GPU); combine sums the halves.
__global__ __launch_bounds__(256, 2) void gemm_small(
    const unsigned short* __restrict__ A,
    const unsigned short* __restrict__ BT,
    float* __restrict__ H) {
    __shared__ unsigned short ldsA[128 * 32];
    __shared__ unsigned short ldsB[128 * 32];
    const int KS = DIN / 2;  // 640
    int tid = threadIdx.x;
    int lane = tid & 63, wave = tid >> 6;
    int m0 = blockIdx.y * 128;
    int z = blockIdx.z;
    int wm = (wave >> 1) * 64, wn = (wave & 1) * 64;
    int lr = lane & 15, quad = lane >> 4;

    f32x4 acc[4][4] = {};
    const unsigned short* Abase = A + (size_t)m0 * KPAD + z * KS;
    const unsigned short* Bbase = BT + z * KS;   // n0 = 0, row stride DIN
    float* Cbase = H + (size_t)z * TOKENS * NLOW;

    for (int k0 = 0; k0 < KS; k0 += 32) {
#pragma unroll
        for (int i = 0; i < 2; i++) {
            int c = i * 256 + tid;
            int row = c >> 2;
            int col = (c & 3) << 3;
            async_load16(&ldsA[(i * 256 + wave * 64) * 8],
                         Abase + (size_t)row * KPAD + k0 + col);
            async_load16(&ldsB[(i * 256 + wave * 64) * 8],
                         Bbase + (size_t)row * DIN + k0 + col);
        }
        __syncthreads();
        bf16x8 af[4], bf[4];
#pragma unroll
        for (int mi = 0; mi < 4; mi++)
            af[mi] = *(const bf16x8*)&ldsA[(wm + mi * 16 + lr) * 32 + quad * 8];
#pragma unroll
        for (int ni = 0; ni < 4; ni++)
            bf[ni] = *(const bf16x8*)&ldsB[(wn + ni * 16 + lr) * 32 + quad * 8];
#pragma unroll
        for (int mi = 0; mi < 4; mi++)
#pragma unroll
            for (int ni = 0; ni < 4; ni++)
                acc[mi][ni] = __builtin_amdgcn_mfma_f32_16x16x32_bf16(
                    af[mi], bf[ni], acc[mi][ni], 0, 0, 0);
        __syncthreads();
    }
#pragma unroll
    for (int ni = 0; ni < 4; ni++) {
        int gn = wn + ni * 16 + lr;
#pragma unroll
        for (int mi = 0; mi < 4; mi++) {
            int gm = m0 + wm + mi * 16 + quad * 4;
            f32x4 v = acc[mi][ni];
#pragma unroll
            for (int r = 0; r < 4; r++)
                Cbase[(size_t)(gm + r) * NLOW + gn] = v[r];
        }
    }
}

// ---------- big GEMM: 256x256 tile, BK=64, 8 waves, pipelined (T1+T2+T3/T4+T5) ----------
// C[m,n] = A[m,:KPAD] @ WcatT[n,:KPAD]^T + bias[n]; raw s_barrier + counted vmcnt,
// XOR-swizzled LDS (chunk ^= row&7) for conflict-free ds_read_b128.

#define READ_AQ(AQ, MB) do { \
    AQ[0][0] = rdA(a_cur, (MB) + 0, 0); AQ[0][1] = rdA(a_cur, (MB) + 0, 1); \
    AQ[1][0] = rdA(a_cur, (MB) + 1, 0); AQ[1][1] = rdA(a_cur, (MB) + 1, 1); \
} while (0)

#define MFMA_QUAD(AQ, MB) do { \
    _Pragma("unroll") for (int ks_ = 0; ks_ < 2; ks_++) \
    _Pragma("unroll") for (int mq_ = 0; mq_ < 2; mq_++) \
    _Pragma("unroll") for (int ni_ = 0; ni_ < 4; ni_++) \
        acc[(MB) + mq_][ni_] = __builtin_amdgcn_mfma_f32_16x16x32_bf16( \
            AQ[mq_][ks_], bfr[ni_][ks_], acc[(MB) + mq_][ni_], 0, 0, 0); \
} while (0)

__global__ __launch_bounds__(512, 2) void gemm256(
    const unsigned short* __restrict__ A,
    const unsigned short* __restrict__ BT,
    const float* __restrict__ bias,
    float* __restrict__ C) {
    __shared__ unsigned short lA[2][256 * 64];   // 64 KB
    __shared__ unsigned short lB[2][256 * 64];   // 64 KB  (128 KB total, 1 block/CU)

    int tid = threadIdx.x;
    int lane = tid & 63, wave = tid >> 6;
    int bid = blockIdx.x;
    // XCD swizzle (960 % 8 == 0, bijective): XCD x owns m-tiles [8x, 8x+8);
    // n iterates slowest so 8 m-blocks share a hot 0.72 MB B panel in L2.
    int xcd = bid & 7, lid = bid >> 3;
    int mt = xcd * 8 + (lid & 7);   // 0..63
    int nt = lid >> 3;              // 0..14
    int m0 = mt * 256, n0 = nt * 256;

    int wm = (wave >> 2) * 128, wn = (wave & 3) * 64;   // 2M x 4N waves, 128x64 each
    int lr = lane & 15, quad = lane >> 4;
    int swz = (lr & 7) << 4;

    // Staging: each global_load_lds moves 1 KB = 8 rows x 128 B per wave; lane l
    // writes LDS chunk l%8 of row l/8, so the global source takes chunk (l%8)^(l/8)
    // (pre-swizzled source; LDS stays linear per m104/m173).
    int sr = lane >> 3;
    int sc = (lane & 7) ^ sr;
    const unsigned short* aSrc = A + (size_t)(m0 + wave * 32 + sr) * KPAD + sc * 8;
    const unsigned short* bSrc = BT + (size_t)(n0 + wave * 32 + sr) * KPAD + sc * 8;

    auto stA4 = [&](unsigned short* dst, int k0) {
#pragma unroll
        for (int i = 0; i < 4; i++)
            async_load16(dst + (size_t)(wave * 32 + i * 8) * 64,
                         aSrc + (size_t)(i * 8) * KPAD + k0);
    };
    auto stB1 = [&](unsigned short* dst, int k0, int i) {
        async_load16(dst + (size_t)(wave * 32 + i * 8) * 64,
                     bSrc + (size_t)(i * 8) * KPAD + k0);
    };
    // Fragment read, swizzle-aware: LDS[row, c] holds source chunk c ^ (row&7);
    // row&7 == lr&7 for all frags (wm, mi*16 multiples of 8) -> lane-constant XOR.
    auto rdA = [&](const unsigned short* base, int mi, int ks) -> bf16x8 {
        int row = wm + mi * 16 + lr;
        int off = row * 128 + (((ks << 6) | (quad << 4)) ^ swz);
        return *(const bf16x8*)((const char*)base + off);
    };
    auto rdB = [&](const unsigned short* base, int ni, int ks) -> bf16x8 {
        int row = wn + ni * 16 + lr;
        int off = row * 128 + (((ks << 6) | (quad << 4)) ^ swz);
        return *(const bf16x8*)((const char*)base + off);
    };

    f32x4 acc[8][4] = {};

    // Prologue: A(0),B(0) -> buf0; B(1) -> buf1 stays in flight across the barrier.
    stA4(&lA[0][0], 0);
#pragma unroll
    for (int i = 0; i < 4; i++) stB1(&lB[0][0], 0, i);
#pragma unroll
    for (int i = 0; i < 4; i++) stB1(&lB[1][0], 64, i);
    asm volatile("s_waitcnt vmcnt(4)" ::: "memory");   // A(0),B(0) resident
    SB(); BAR(); SB();

    const int nkt = KPAD / 64;  // 22
#pragma unroll 2
    for (int t = 0; t < nkt; ++t) {
        const int ct = t & 1;
        unsigned short* a_cur = &lA[ct][0];
        unsigned short* b_cur = &lB[ct][0];
        unsigned short* a_nxt = &lA[ct ^ 1][0];
        int k0 = t * 64;

        // P1: all B frags + A quads 0,1; stage A(t+1) into the other buffer
        // (its A region was last read in group t-1, freed by that group's barrier).
        bf16x8 bfr[4][2];
#pragma unroll
        for (int ni = 0; ni < 4; ni++) {
            bfr[ni][0] = rdB(b_cur, ni, 0);
            bfr[ni][1] = rdB(b_cur, ni, 1);
        }
        SB();  // pin: B reads are the 8 oldest lgkm ops for the count below
        bf16x8 aq0[2][2], aq1[2][2], aq2[2][2], aq3[2][2];
        READ_AQ(aq0, 0);
        READ_AQ(aq1, 2);
        if (t + 1 < nkt) stA4(a_nxt, k0 + 64);

        // P2: MFMA quad 0 (compiler's lgkm wait before it retires the B reads)
        READ_AQ(aq2, 4);
        __builtin_amdgcn_s_setprio(1); MFMA_QUAD(aq0, 0); __builtin_amdgcn_s_setprio(0);
        asm volatile("s_waitcnt lgkmcnt(8)" ::: "memory");  // all B reads retired
        SB(); BAR(); SB();  // -> current buffer's B region is now free to restage

        // P3: stage B(t+2) into current buffer's B region (2-group lead)
        READ_AQ(aq3, 6);
        if (t + 2 < nkt) { stB1(b_cur, k0 + 128, 0); stB1(b_cur, k0 + 128, 1); }
        __builtin_amdgcn_s_setprio(1); MFMA_QUAD(aq1, 2); __builtin_amdgcn_s_setprio(0);

        // P4
        if (t + 2 < nkt) { stB1(b_cur, k0 + 128, 2); stB1(b_cur, k0 + 128, 3); }
        __builtin_amdgcn_s_setprio(1); MFMA_QUAD(aq2, 4); __builtin_amdgcn_s_setprio(0);

        // P5
        __builtin_amdgcn_s_setprio(1); MFMA_QUAD(aq3, 6); __builtin_amdgcn_s_setprio(0);

        // Group end: per-wave vm queue = [B(t+1)x4, A(t+1)x4, B(t+2)x4];
        // vmcnt(4) retires exactly what group t+1 reads, keeps B(t+2) in flight
        // (never drain to 0 mid-loop). Last two groups have no B(t+2): drain fully.
        if (t + 2 < nkt) asm volatile("s_waitcnt vmcnt(4) lgkmcnt(0)" ::: "memory");
        else             asm volatile("s_waitcnt vmcnt(0) lgkmcnt(0)" ::: "memory");
        SB(); BAR(); SB();
    }

    // Epilogue: C/D layout col = lane&15, row = quad*4 + reg (verified mapping)
#pragma unroll
    for (int mi = 0; mi < 8; mi++) {
        int gm = m0 + wm + mi * 16 + quad * 4;
#pragma unroll
        for (int ni = 0; ni < 4; ni++) {
            int gn = n0 + wn + ni * 16 + lr;
            float bv = bias[gn];
            f32x4 v = acc[mi][ni];
#pragma unroll
            for (int r = 0; r < 4; r++)
                C[(size_t)(gm + r) * DOUT + gn] = v[r] + bv;
        }
    }
}

extern "C" void kernel_launch(void* const* d_in, const int* in_sizes, int n_in,
                              void* d_out, int out_size, void* d_ws, size_t ws_size,
                              hipStream_t stream) {
    const float* x         = (const float*)d_in[0];
    const float* base_w    = (const float*)d_in[1];
    const float* base_b    = (const float*)d_in[2];
    const float* shared_w1 = (const float*)d_in[3];
    const float* shared_w2 = (const float*)d_in[4];
    const float* routed_w1 = (const float*)d_in[5];
    const float* routed_w2 = (const float*)d_in[6];
    const float* router_w  = (const float*)d_in[7];
    const float* router_b  = (const float*)d_in[8];
    float* out = (float*)d_out;

    char* ws = (char*)d_ws;
    size_t off = 0;
    unsigned short* A     = (unsigned short*)(ws + off); off += (size_t)TOKENS * KPAD * 2;      // 46.1 MB
    unsigned short* WcatT = (unsigned short*)(ws + off); off += (size_t)DOUT * KPAD * 2;        // 10.8 MB
    unsigned short* W1T   = (unsigned short*)(ws + off); off += (size_t)NLOW * DIN * 2;         // 0.33 MB
    float* H              = (float*)(ws + off);          off += (size_t)2 * TOKENS * NLOW * 4;  // 16.8 MB
    float* cw             = (float*)(ws + off);          off += (size_t)TOKENS * NEXP * 4;      // 0.39 MB

    prep_w2t<<<dim3(KPAD / 32, DOUT / 32), dim3(32, 8), 0, stream>>>(
        base_w, shared_w2, routed_w2, WcatT);
    prep_w1t<<<dim3(DIN / 32, NLOW / 32), dim3(32, 8), 0, stream>>>(
        shared_w1, routed_w1, W1T);
    router_kernel<<<TOKENS / 8, 256, 0, stream>>>(x, router_w, router_b, A, cw);
    gemm_small<<<dim3(1, TOKENS / 128, 2), 256, 0, stream>>>(A, W1T, H);
    combine_kernel<<<(TOKENS * 112) / 256, 256, 0, stream>>>(H, cw, A);
    gemm256<<<(TOKENS / 256) * (DOUT / 256), 512, 0, stream>>>(A, WcatT, base_b, out);
}